// Round 3
// baseline (186.311 us; speedup 1.0000x reference)
//
#include <hip/hip_runtime.h>
#include <hip/hip_cooperative_groups.h>
#include <math.h>

namespace cg = cooperative_groups;

#define H 1024
#define V 50257
#define S 2048
#define NB 256             // 1 block/CU -- big margin for cooperative launch
#define NT 1024            // 16 waves/block
#define RPB 197            // ceil(V/NB) logit rows per block

// ---- fused-kernel ws float offsets ----
#define O_COEFF  0                   // S
#define O_CTXP   2048                // 32*H
#define O_Z      35840               // H
#define O_HNEW   36864               // H
#define O_PART   37888               // 2*NB
#define O_LOGITS 38464               // V

// ---- fallback-chain ws float offsets (round-1 layout, known good) ----
#define F_HDOT   65536
#define F_COEFF  (F_HDOT + 64)
#define F_CTXP   (F_COEFF + S)
#define F_CTX    (F_CTXP + 64*H)
#define F_Z      (F_CTX + H)
#define F_GATES  (F_Z + H)
#define F_HNEW   (F_GATES + 4*H)
#define F_LOGITS (F_HNEW + H)
#define F_PMAX   (((F_LOGITS + V) + 63) & ~63)
#define F_SCAL   (F_PMAX + 64)

__device__ inline float wred_sum(float v) {
    for (int o = 32; o > 0; o >>= 1) v += __shfl_down(v, o, 64);
    return v;
}
__device__ inline float wred_max(float v) {
    for (int o = 32; o > 0; o >>= 1) v = fmaxf(v, __shfl_down(v, o, 64));
    return v;
}
__device__ inline float sigm(float x) { return 1.f / (1.f + expf(-x)); }

// ======================= fused cooperative kernel =======================
__global__ __launch_bounds__(NT, 4) void fused(
    const int* __restrict__ ids, const float* __restrict__ h0,
    const float* __restrict__ c0, const float* __restrict__ enc,
    const float* __restrict__ emb, const float* __restrict__ attn_W,
    const float* __restrict__ attn_b, const float* __restrict__ comb_W,
    const float* __restrict__ comb_b, const float* __restrict__ W_ih,
    const float* __restrict__ W_hh, const float* __restrict__ b_ih,
    const float* __restrict__ b_hh, const float* __restrict__ out_W,
    const float* __restrict__ out_b, float* __restrict__ out,
    float* __restrict__ ws)
{
    cg::grid_group grid = cg::this_grid();
    const int b = blockIdx.x, t = threadIdx.x;
    const int lane = t & 63, wave = t >> 6;
    __shared__ float sred[16];
    __shared__ float sm[16], ss[16];
    __shared__ __align__(16) float sarr[1024];
    __shared__ __align__(16) float sctx[1024];

    // ---- P1: hdot (block-redundant) + coeff[s] for s in [b*8, b*8+8) ----
    {
        float p = 0.f;
        if (t < 256) {
            float4 hv = ((const float4*)h0)[t];
            float4 wv = ((const float4*)(attn_W + H))[t];
            p = hv.x*wv.x + hv.y*wv.y + hv.z*wv.z + hv.w*wv.w;
        }
        p = wred_sum(p);
        if (lane == 0) sred[wave] = p;
        __syncthreads();
        float hdot = attn_b[0];
        #pragma unroll
        for (int i2 = 0; i2 < 16; ++i2) hdot += sred[i2];
        if (wave < 8) {
            int s = b * 8 + wave;
            const float4* e4 = (const float4*)(enc + (size_t)s * H);
            const float4* w0 = (const float4*)attn_W;
            float acc = 0.f;
            #pragma unroll
            for (int kk = 0; kk < 4; ++kk) {
                float4 e = e4[kk*64 + lane], w = w0[kk*64 + lane];
                acc += e.x*w.x + e.y*w.y + e.z*w.z + e.w*w.w;
            }
            acc = wred_sum(acc);
            if (lane == 0) ws[O_COEFF + s] = acc + hdot;
        }
    }
    grid.sync();

    // ---- P2: ctxp[ch][j] partials; block = (chunk of 64 s) x (slice of 128 j) ----
    {
        int ch = b >> 3, slice = b & 7;
        int jj = t & 127, sg = t >> 7;              // 8 s-groups of 8
        int j = slice * 128 + jj;
        int s0 = ch * 64 + sg * 8;
        float acc = 0.f;
        #pragma unroll
        for (int k = 0; k < 8; ++k)
            acc += enc[(size_t)(s0 + k) * H + j] * ws[O_COEFF + s0 + k];
        sarr[sg * 128 + jj] = acc;
        __syncthreads();
        if (t < 128) {
            float a2 = 0.f;
            #pragma unroll
            for (int g = 0; g < 8; ++g) a2 += sarr[g * 128 + t];
            ws[O_CTXP + ch * H + slice * 128 + t] = a2;
        }
    }
    grid.sync();

    // ---- P3 (block-redundant): ctx[j] = sum_ch ctxp ; into LDS ----
    {
        float a2 = 0.f;
        #pragma unroll
        for (int c2 = 0; c2 < 32; ++c2) a2 += ws[O_CTXP + c2 * H + t];
        sctx[t] = a2;
    }
    __syncthreads();

    // ---- P4: z = relu(comb_W @ [x; ctx] + b); 4 rows/block, 4 waves/row ----
    {
        int tok = ids[0];
        int i = b * 4 + (wave & 3), q = wave >> 2;   // row, k-quarter
        const float4* wrow = (const float4*)(comb_W + (size_t)i * 2 * H);
        float acc = 0.f;
        if (q < 2) {
            const float4* x4 = (const float4*)(emb + (size_t)tok * H);
            #pragma unroll
            for (int kk = 0; kk < 2; ++kk) {
                int k4 = q * 128 + kk * 64 + lane;
                float4 w = wrow[k4], a = x4[k4];
                acc += w.x*a.x + w.y*a.y + w.z*a.z + w.w*a.w;
            }
        } else {
            const float4* c4 = (const float4*)sctx;
            #pragma unroll
            for (int kk = 0; kk < 2; ++kk) {
                int k4 = q * 128 + kk * 64 + lane;
                float4 w = wrow[k4], a = c4[k4 - 256];
                acc += w.x*a.x + w.y*a.y + w.z*a.z + w.w*a.w;
            }
        }
        acc = wred_sum(acc);
        if (lane == 0) sred[wave] = acc;
        __syncthreads();
        if (t < 4) {
            float zz = sred[t] + sred[t+4] + sred[t+8] + sred[t+12] + comb_b[b*4 + t];
            ws[O_Z + b*4 + t] = fmaxf(zz, 0.f);
        }
    }
    grid.sync();

    // ---- P5: gates + LSTM pointwise; block owns 4 hidden j, wave = (gate, j) ----
    {
        int jloc = wave & 3, gate = wave >> 2;
        int j = b * 4 + jloc, row = gate * H + j;
        const float4* wi = (const float4*)(W_ih + (size_t)row * H);
        const float4* wh = (const float4*)(W_hh + (size_t)row * H);
        const float4* zv = (const float4*)(ws + O_Z);
        const float4* hv = (const float4*)h0;
        float acc = 0.f;
        #pragma unroll
        for (int kk = 0; kk < 4; ++kk) {
            int k4 = kk * 64 + lane;
            float4 a = wi[k4], z4 = zv[k4];
            acc += a.x*z4.x + a.y*z4.y + a.z*z4.z + a.w*z4.w;
            float4 c2 = wh[k4], h4 = hv[k4];
            acc += c2.x*h4.x + c2.y*h4.y + c2.z*h4.z + c2.w*h4.w;
        }
        acc = wred_sum(acc);
        if (lane == 0) sred[wave] = acc + b_ih[row] + b_hh[row];
        __syncthreads();
        if (t < 4) {
            int j2 = b * 4 + t;
            float ig = sigm(sred[t]);
            float fg = sigm(sred[4 + t]);
            float gg = tanhf(sred[8 + t]);
            float og = sigm(sred[12 + t]);
            float cn = fg * c0[j2] + ig * gg;
            float hn = og * tanhf(cn);
            out[V + j2]     = hn;
            out[V + H + j2] = cn;
            ws[O_HNEW + j2] = hn;
        }
    }
    grid.sync();

    // ---- P6: logits GEMV + per-block online (m, sumexp) partial ----
    {
        const float4* hv = (const float4*)(ws + O_HNEW);
        float4 hr[4];
        #pragma unroll
        for (int kk = 0; kk < 4; ++kk) hr[kk] = hv[kk * 64 + lane];
        float m = -1e30f, ssum = 0.f;
        int v0 = b * RPB;
        for (int r = wave; r < RPB; r += 16) {
            int v = v0 + r;
            if (v >= V) break;
            const float4* w4 = (const float4*)(out_W + (size_t)v * H);
            float acc = 0.f;
            #pragma unroll
            for (int kk = 0; kk < 4; ++kk) {
                float4 w = w4[kk * 64 + lane];
                float4 a = hr[kk];
                acc += w.x*a.x + w.y*a.y + w.z*a.z + w.w*a.w;
            }
            acc = wred_sum(acc);
            if (lane == 0) {
                float lg = acc + out_b[v];
                ws[O_LOGITS + v] = lg;
                float M = fmaxf(m, lg);
                ssum = ssum * expf(m - M) + expf(lg - M);
                m = M;
            }
        }
        if (lane == 0) { sm[wave] = m; ss[wave] = ssum; }
        __syncthreads();
        if (t == 0) {
            float M = sm[0], Ssum = ss[0];
            #pragma unroll
            for (int w2 = 1; w2 < 16; ++w2) {
                float m2 = sm[w2], s2 = ss[w2];
                float MM = fmaxf(M, m2);
                Ssum = Ssum * expf(M - MM) + s2 * expf(m2 - MM);
                M = MM;
            }
            ws[O_PART + 2 * b]     = M;
            ws[O_PART + 2 * b + 1] = Ssum;
        }
    }
    grid.sync();

    // ---- P7 (block-redundant): combine 256 partials -> lse; P8: subtract ----
    {
        float m = -1e30f, s2v = 0.f;
        if (t < NB) { m = ws[O_PART + 2 * t]; s2v = ws[O_PART + 2 * t + 1]; }
        for (int o = 32; o > 0; o >>= 1) {
            float m2 = __shfl_down(m, o, 64), s2 = __shfl_down(s2v, o, 64);
            float M = fmaxf(m, m2);
            s2v = s2v * expf(m - M) + s2 * expf(m2 - M);
            m = M;
        }
        if (lane == 0) { sm[wave] = m; ss[wave] = s2v; }
        __syncthreads();
        if (t == 0) {
            float M = sm[0], Ssum = ss[0];
            #pragma unroll
            for (int w2 = 1; w2 < 16; ++w2) {
                float m2 = sm[w2], s2 = ss[w2];
                float MM = fmaxf(M, m2);
                Ssum = Ssum * expf(M - MM) + s2 * expf(m2 - MM);
                M = MM;
            }
            sred[0] = M + logf(Ssum);
        }
        __syncthreads();
        float lse = sred[0];
        int v = b * RPB + t;
        if (t < RPB && v < V) out[v] = ws[O_LOGITS + v] - lse;
    }
}

// ======================= fallback chain (round-1, verified) =======================
__global__ void k_hdot(const float* __restrict__ h, const float* __restrict__ attn_W,
                       const float* __restrict__ attn_b, float* __restrict__ ws) {
    int t = threadIdx.x;
    float s = 0.f;
    for (int k = t; k < H; k += 256) s += h[k] * attn_W[H + k];
    __shared__ float red[4];
    s = wred_sum(s);
    if ((t & 63) == 0) red[t >> 6] = s;
    __syncthreads();
    if (t == 0) ws[F_HDOT] = red[0] + red[1] + red[2] + red[3] + attn_b[0];
}
__global__ void k_coeff(const float* __restrict__ enc, const float* __restrict__ attn_W,
                        float* __restrict__ ws) {
    int sidx = blockIdx.x, t = threadIdx.x;
    const float4* erow = (const float4*)(enc + (size_t)sidx * H);
    const float4* wrow = (const float4*)attn_W;
    float4 e = erow[t], w = wrow[t];
    float s = e.x*w.x + e.y*w.y + e.z*w.z + e.w*w.w;
    __shared__ float red[4];
    s = wred_sum(s);
    if ((t & 63) == 0) red[t >> 6] = s;
    __syncthreads();
    if (t == 0) ws[F_COEFF + sidx] = red[0] + red[1] + red[2] + red[3] + ws[F_HDOT];
}
__global__ void k_ctxp(const float* __restrict__ enc, float* __restrict__ ws) {
    int j = blockIdx.x * 256 + threadIdx.x;
    int ch = blockIdx.y;
    float acc = 0.f;
    int s0 = ch * 32;
    for (int s = s0; s < s0 + 32; ++s)
        acc += enc[(size_t)s * H + j] * ws[F_COEFF + s];
    ws[F_CTXP + ch * H + j] = acc;
}
__global__ void k_ctx(float* __restrict__ ws) {
    int j = blockIdx.x * 256 + threadIdx.x;
    float acc = 0.f;
    for (int ch = 0; ch < 64; ++ch) acc += ws[F_CTXP + ch * H + j];
    ws[F_CTX + j] = acc;
}
__global__ void k_z(const float* __restrict__ emb, const int* __restrict__ ids,
                    const float* __restrict__ comb_W, const float* __restrict__ comb_b,
                    float* __restrict__ ws) {
    int i = blockIdx.x * 4 + (threadIdx.x >> 6);
    int lane = threadIdx.x & 63;
    int tok = ids[0];
    const float* x   = emb + (size_t)tok * H;
    const float* ctx = ws + F_CTX;
    const float4* wrow = (const float4*)(comb_W + (size_t)i * 2 * H);
    float s = 0.f;
    #pragma unroll
    for (int kk = 0; kk < 8; ++kk) {
        int k4 = kk * 64 + lane;
        float4 w = wrow[k4];
        int k = k4 * 4;
        const float* a = (k < H) ? (x + k) : (ctx + (k - H));
        float4 av = *(const float4*)a;
        s += w.x*av.x + w.y*av.y + w.z*av.z + w.w*av.w;
    }
    s = wred_sum(s);
    if (lane == 0) ws[F_Z + i] = fmaxf(s + comb_b[i], 0.f);
}
__global__ void k_gates(const float* __restrict__ W_ih, const float* __restrict__ W_hh,
                        const float* __restrict__ b_ih, const float* __restrict__ b_hh,
                        const float* __restrict__ h, float* __restrict__ ws) {
    int i = blockIdx.x * 4 + (threadIdx.x >> 6);
    int lane = threadIdx.x & 63;
    const float4* wi = (const float4*)(W_ih + (size_t)i * H);
    const float4* wh = (const float4*)(W_hh + (size_t)i * H);
    const float4* zv = (const float4*)(ws + F_Z);
    const float4* hv = (const float4*)h;
    float s = 0.f;
    #pragma unroll
    for (int kk = 0; kk < 4; ++kk) {
        int k4 = kk * 64 + lane;
        float4 a = wi[k4], b4 = zv[k4];
        s += a.x*b4.x + a.y*b4.y + a.z*b4.z + a.w*b4.w;
        float4 c2 = wh[k4], d = hv[k4];
        s += c2.x*d.x + c2.y*d.y + c2.z*d.z + c2.w*d.w;
    }
    s = wred_sum(s);
    if (lane == 0) ws[F_GATES + i] = s + b_ih[i] + b_hh[i];
}
__global__ void k_lstm(const float* __restrict__ c0, float* __restrict__ ws,
                       float* __restrict__ out) {
    int j = blockIdx.x * 256 + threadIdx.x;
    const float* g = ws + F_GATES;
    float ig = sigm(g[j]);
    float fg = sigm(g[H + j]);
    float gg = tanhf(g[2*H + j]);
    float og = sigm(g[3*H + j]);
    float cn = fg * c0[j] + ig * gg;
    float hn = og * tanhf(cn);
    out[V + j]     = hn;
    out[V + H + j] = cn;
    ws[F_HNEW + j] = hn;
}
__global__ void k_logits(const float* __restrict__ out_W, const float* __restrict__ out_b,
                         float* __restrict__ ws) {
    int v = blockIdx.x * 4 + (threadIdx.x >> 6);
    if (v >= V) return;
    int lane = threadIdx.x & 63;
    const float4* w  = (const float4*)(out_W + (size_t)v * H);
    const float4* hv = (const float4*)(ws + F_HNEW);
    float s = 0.f;
    #pragma unroll
    for (int kk = 0; kk < 4; ++kk) {
        int k4 = kk * 64 + lane;
        float4 a = w[k4], b4 = hv[k4];
        s += a.x*b4.x + a.y*b4.y + a.z*b4.z + a.w*b4.w;
    }
    s = wred_sum(s);
    if (lane == 0) ws[F_LOGITS + v] = s + out_b[v];
}
__global__ void k_max(float* __restrict__ ws) {
    int t = blockIdx.x * 256 + threadIdx.x;
    float m = -1e30f;
    for (int v = t; v < V; v += 64 * 256) m = fmaxf(m, ws[F_LOGITS + v]);
    __shared__ float red[4];
    m = wred_max(m);
    if ((threadIdx.x & 63) == 0) red[threadIdx.x >> 6] = m;
    __syncthreads();
    if (threadIdx.x == 0)
        ws[F_PMAX + blockIdx.x] = fmaxf(fmaxf(red[0], red[1]), fmaxf(red[2], red[3]));
}
__global__ void k_lse(float* __restrict__ ws) {
    int t = threadIdx.x;
    __shared__ float smax;
    float m = -1e30f;
    if (t < 64) m = ws[F_PMAX + t];
    m = wred_max(m);
    if (t == 0) smax = m;
    __syncthreads();
    float maxv = smax;
    float s = 0.f;
    for (int v = t; v < V; v += 256) s += expf(ws[F_LOGITS + v] - maxv);
    __shared__ float red[4];
    s = wred_sum(s);
    if ((t & 63) == 0) red[t >> 6] = s;
    __syncthreads();
    if (t == 0) {
        ws[F_SCAL]     = maxv;
        ws[F_SCAL + 1] = logf(red[0] + red[1] + red[2] + red[3]);
    }
}
__global__ void k_logp(const float* __restrict__ ws, float* __restrict__ out) {
    int v = blockIdx.x * 256 + threadIdx.x;
    if (v < V) out[v] = ws[F_LOGITS + v] - ws[F_SCAL] - ws[F_SCAL + 1];
}

extern "C" void kernel_launch(void* const* d_in, const int* in_sizes, int n_in,
                              void* d_out, int out_size, void* d_ws, size_t ws_size,
                              hipStream_t stream) {
    const int*   ids    = (const int*)  d_in[0];
    const float* h0     = (const float*)d_in[1];
    const float* c0     = (const float*)d_in[2];
    const float* enc    = (const float*)d_in[3];
    const float* emb    = (const float*)d_in[4];
    const float* attn_W = (const float*)d_in[5];
    const float* attn_b = (const float*)d_in[6];
    const float* comb_W = (const float*)d_in[7];
    const float* comb_b = (const float*)d_in[8];
    const float* W_ih   = (const float*)d_in[9];
    const float* W_hh   = (const float*)d_in[10];
    const float* b_ih   = (const float*)d_in[11];
    const float* b_hh   = (const float*)d_in[12];
    const float* out_W  = (const float*)d_in[13];
    const float* out_b  = (const float*)d_in[14];
    float* out = (float*)d_out;
    float* ws  = (float*)d_ws;

    void* args[] = {
        (void*)&ids, (void*)&h0, (void*)&c0, (void*)&enc, (void*)&emb,
        (void*)&attn_W, (void*)&attn_b, (void*)&comb_W, (void*)&comb_b,
        (void*)&W_ih, (void*)&W_hh, (void*)&b_ih, (void*)&b_hh,
        (void*)&out_W, (void*)&out_b, (void*)&out, (void*)&ws
    };
    hipError_t e = hipLaunchCooperativeKernel((void*)fused, dim3(NB), dim3(NT),
                                              args, 0, stream);
    if (e != hipSuccess) {
        (void)hipGetLastError();   // clear sticky error, use verified chain
        k_hdot  <<<1, 256, 0, stream>>>(h0, attn_W, attn_b, ws);
        k_coeff <<<S, 256, 0, stream>>>(enc, attn_W, ws);
        k_ctxp  <<<dim3(H/256, 64), 256, 0, stream>>>(enc, ws);
        k_ctx   <<<H/256, 256, 0, stream>>>(ws);
        k_z     <<<H/4, 256, 0, stream>>>(emb, ids, comb_W, comb_b, ws);
        k_gates <<<4*H/4, 256, 0, stream>>>(W_ih, W_hh, b_ih, b_hh, h0, ws);
        k_lstm  <<<H/256, 256, 0, stream>>>(c0, ws, out);
        k_logits<<<(V + 3)/4, 256, 0, stream>>>(out_W, out_b, ws);
        k_max   <<<64, 256, 0, stream>>>(ws);
        k_lse   <<<1, 256, 0, stream>>>(ws);
        k_logp  <<<(V + 255)/256, 256, 0, stream>>>(ws, out);
    }
}

// Round 4
// 66.360 us; speedup vs baseline: 2.8076x; 2.8076x over previous
//
#include <hip/hip_runtime.h>
#include <math.h>

#define H 1024
#define V 50257
#define S 2048
#define NCH 64            // s-chunks of 32 rows for ctxp partials
#define LB 6283           // ceil(V/8) logits blocks

// ws float offsets (all 16B-aligned where read as float4)
#define O_CTXP   0                    // NCH*H = 65536
#define O_Z      65536                // H
#define O_HNEW   66560                // H
#define O_PART   67584                // 2*LB
#define O_LOGITS 80152                // V

__device__ inline float wred_sum(float v) {
    for (int o = 32; o > 0; o >>= 1) v += __shfl_down(v, o, 64);
    return v;
}
__device__ inline float sigm(float x) { return 1.f / (1.f + expf(-x)); }

// ---- K1: hdot (redundant) + coeff for own 32-row chunk (LDS) + ctxp partial ----
__global__ __launch_bounds__(256) void k_attn(const float* __restrict__ enc,
        const float* __restrict__ h0, const float* __restrict__ attn_W,
        const float* __restrict__ attn_b, float* __restrict__ ws) {
    const int ch = blockIdx.x, t = threadIdx.x, lane = t & 63, wave = t >> 6;
    __shared__ float scoef[32];
    __shared__ float sred[4];

    // hdot = dot(h0, attn_W[H:2H]) + attn_b, block-redundant
    float4 hv = ((const float4*)h0)[t];
    float4 wv = ((const float4*)(attn_W + H))[t];
    float p = hv.x*wv.x + hv.y*wv.y + hv.z*wv.z + hv.w*wv.w;
    p = wred_sum(p);
    if (lane == 0) sred[wave] = p;
    __syncthreads();
    const float hdot = sred[0] + sred[1] + sred[2] + sred[3] + attn_b[0];

    // coeff[s] for the chunk's 32 rows; each wave owns 8 rows
    const float4* w0 = (const float4*)attn_W;
    const int s0 = ch * 32;
    for (int r = 0; r < 8; ++r) {
        int s = s0 + wave * 8 + r;
        const float4* e4 = (const float4*)(enc + (size_t)s * H);
        float acc = 0.f;
        #pragma unroll
        for (int kk = 0; kk < 4; ++kk) {
            float4 e = e4[kk*64 + lane], w = w0[kk*64 + lane];
            acc += e.x*w.x + e.y*w.y + e.z*w.z + e.w*w.w;
        }
        acc = wred_sum(acc);
        if (lane == 0) scoef[wave * 8 + r] = acc + hdot;
    }
    __syncthreads();

    // ctxp[ch][j] = sum_s coeff[s] * enc[s][j]  (2nd pass over same rows, L2-hot)
    float4 a4 = make_float4(0.f, 0.f, 0.f, 0.f);
    for (int r = 0; r < 32; ++r) {
        float c = scoef[r];
        float4 e = ((const float4*)(enc + (size_t)(s0 + r) * H))[t];
        a4.x += c * e.x; a4.y += c * e.y; a4.z += c * e.z; a4.w += c * e.w;
    }
    ((float4*)(ws + O_CTXP + ch * H))[t] = a4;
}

// ---- K2: ctx reduce (block-redundant, L2-hot) + z = relu(comb_W @ [x;ctx] + b) ----
__global__ __launch_bounds__(256) void k_z(const float* __restrict__ emb,
        const int* __restrict__ ids, const float* __restrict__ comb_W,
        const float* __restrict__ comb_b, float* __restrict__ ws) {
    const int b = blockIdx.x, t = threadIdx.x, lane = t & 63, wave = t >> 6;
    __shared__ __align__(16) float sctx[H];
    float4 a4 = make_float4(0.f, 0.f, 0.f, 0.f);
    #pragma unroll 8
    for (int ch = 0; ch < NCH; ++ch) {
        float4 v = ((const float4*)(ws + O_CTXP + ch * H))[t];
        a4.x += v.x; a4.y += v.y; a4.z += v.z; a4.w += v.w;
    }
    ((float4*)sctx)[t] = a4;
    __syncthreads();

    const int tok = ids[0];
    const int i = b * 4 + wave;
    const float4* wrow = (const float4*)(comb_W + (size_t)i * 2 * H);
    const float4* x4 = (const float4*)(emb + (size_t)tok * H);
    const float4* c4 = (const float4*)sctx;
    float acc = 0.f;
    #pragma unroll
    for (int kk = 0; kk < 4; ++kk) {
        int k4 = kk * 64 + lane;
        float4 w = wrow[k4], a = x4[k4];
        acc += w.x*a.x + w.y*a.y + w.z*a.z + w.w*a.w;
        float4 w2 = wrow[256 + k4], a2 = c4[k4];
        acc += w2.x*a2.x + w2.y*a2.y + w2.z*a2.z + w2.w*a2.w;
    }
    acc = wred_sum(acc);
    if (lane == 0) ws[O_Z + i] = fmaxf(acc + comb_b[i], 0.f);
}

// ---- K3: gates GEMV (wave per gate) + LSTM pointwise; block = hidden index j ----
__global__ __launch_bounds__(256) void k_gates_lstm(const float* __restrict__ W_ih,
        const float* __restrict__ W_hh, const float* __restrict__ b_ih,
        const float* __restrict__ b_hh, const float* __restrict__ h0,
        const float* __restrict__ c0, float* __restrict__ ws, float* __restrict__ out) {
    const int j = blockIdx.x, t = threadIdx.x, lane = t & 63, g = t >> 6;
    __shared__ float sg[4];
    const int row = g * H + j;
    const float4* wi = (const float4*)(W_ih + (size_t)row * H);
    const float4* wh = (const float4*)(W_hh + (size_t)row * H);
    const float4* zv = (const float4*)(ws + O_Z);
    const float4* hv = (const float4*)h0;
    float acc = 0.f;
    #pragma unroll
    for (int kk = 0; kk < 4; ++kk) {
        int k4 = kk * 64 + lane;
        float4 a = wi[k4], z4 = zv[k4];
        acc += a.x*z4.x + a.y*z4.y + a.z*z4.z + a.w*z4.w;
        float4 c2 = wh[k4], h4 = hv[k4];
        acc += c2.x*h4.x + c2.y*h4.y + c2.z*h4.z + c2.w*h4.w;
    }
    acc = wred_sum(acc);
    if (lane == 0) sg[g] = acc + b_ih[row] + b_hh[row];
    __syncthreads();
    if (t == 0) {
        float ig = sigm(sg[0]);
        float fg = sigm(sg[1]);
        float gg = tanhf(sg[2]);
        float og = sigm(sg[3]);
        float cn = fg * c0[j] + ig * gg;
        float hn = og * tanhf(cn);
        out[V + j]     = hn;
        out[V + H + j] = cn;
        ws[O_HNEW + j] = hn;
    }
}

// ---- K4: logits GEMV, wave per row, + per-block (max, sumexp) partial ----
__global__ __launch_bounds__(512) void k_logits(const float* __restrict__ out_W,
        const float* __restrict__ out_b, float* __restrict__ ws) {
    const int t = threadIdx.x, lane = t & 63, w8 = t >> 6;
    const int v = blockIdx.x * 8 + w8;
    __shared__ float slg[8];
    const float4* hv = (const float4*)(ws + O_HNEW);
    float acc = 0.f;
    if (v < V) {
        const float4* wr = (const float4*)(out_W + (size_t)v * H);
        #pragma unroll
        for (int kk = 0; kk < 4; ++kk) {
            int k4 = kk * 64 + lane;
            float4 w = wr[k4], a = hv[k4];
            acc += w.x*a.x + w.y*a.y + w.z*a.z + w.w*a.w;
        }
    }
    acc = wred_sum(acc);
    if (lane == 0) {
        if (v < V) {
            float lg = acc + out_b[v];
            ws[O_LOGITS + v] = lg;
            slg[w8] = lg;
        } else {
            slg[w8] = -1e30f;
        }
    }
    __syncthreads();
    if (t == 0) {
        float m = slg[0];
        #pragma unroll
        for (int i = 1; i < 8; ++i) m = fmaxf(m, slg[i]);
        float s = 0.f;
        #pragma unroll
        for (int i = 0; i < 8; ++i) s += expf(slg[i] - m);
        ws[O_PART + 2 * blockIdx.x]     = m;
        ws[O_PART + 2 * blockIdx.x + 1] = s;
    }
}

// ---- K5: combine partials -> lse (block-redundant, L2) + subtract ----
__global__ __launch_bounds__(1024) void k_logp(const float* __restrict__ ws,
        float* __restrict__ out) {
    const int t = threadIdx.x, lane = t & 63, wv = t >> 6;
    __shared__ float smm[16], sss[16];
    __shared__ float slse;
    float m = -1e30f, s = 0.f;
    for (int i = t; i < LB; i += 1024) {
        float m2 = ws[O_PART + 2 * i], s2 = ws[O_PART + 2 * i + 1];
        float M = fmaxf(m, m2);
        s = s * expf(m - M) + s2 * expf(m2 - M);
        m = M;
    }
    for (int o = 32; o > 0; o >>= 1) {
        float m2 = __shfl_down(m, o, 64), s2 = __shfl_down(s, o, 64);
        float M = fmaxf(m, m2);
        s = s * expf(m - M) + s2 * expf(m2 - M);
        m = M;
    }
    if (lane == 0) { smm[wv] = m; sss[wv] = s; }
    __syncthreads();
    if (t == 0) {
        float M = smm[0], Ssum = sss[0];
        #pragma unroll
        for (int i = 1; i < 16; ++i) {
            float MM = fmaxf(M, smm[i]);
            Ssum = Ssum * expf(M - MM) + sss[i] * expf(smm[i] - MM);
            M = MM;
        }
        slse = M + logf(Ssum);
    }
    __syncthreads();
    const float lse = slse;
    int v = blockIdx.x * 1024 + t;
    if (v < V) out[v] = ws[O_LOGITS + v] - lse;
}

extern "C" void kernel_launch(void* const* d_in, const int* in_sizes, int n_in,
                              void* d_out, int out_size, void* d_ws, size_t ws_size,
                              hipStream_t stream) {
    const int*   ids    = (const int*)  d_in[0];
    const float* h0     = (const float*)d_in[1];
    const float* c0     = (const float*)d_in[2];
    const float* enc    = (const float*)d_in[3];
    const float* emb    = (const float*)d_in[4];
    const float* attn_W = (const float*)d_in[5];
    const float* attn_b = (const float*)d_in[6];
    const float* comb_W = (const float*)d_in[7];
    const float* comb_b = (const float*)d_in[8];
    const float* W_ih   = (const float*)d_in[9];
    const float* W_hh   = (const float*)d_in[10];
    const float* b_ih   = (const float*)d_in[11];
    const float* b_hh   = (const float*)d_in[12];
    const float* out_W  = (const float*)d_in[13];
    const float* out_b  = (const float*)d_in[14];
    float* out = (float*)d_out;
    float* ws  = (float*)d_ws;

    k_attn      <<<NCH, 256, 0, stream>>>(enc, h0, attn_W, attn_b, ws);
    k_z         <<<256, 256, 0, stream>>>(emb, ids, comb_W, comb_b, ws);
    k_gates_lstm<<<1024, 256, 0, stream>>>(W_ih, W_hh, b_ih, b_hh, h0, c0, ws, out);
    k_logits    <<<LB, 512, 0, stream>>>(out_W, out_b, ws);
    k_logp      <<<64, 1024, 0, stream>>>(ws, out);
}